// Round 2
// baseline (1175.688 us; speedup 1.0000x reference)
//
#include <hip/hip_runtime.h>

#define VOCABN 64
#define EMBN   128
#define HDIM   256
#define NUMIN  7
#define BN     64
#define SN     2048
#define TWOH   512

__device__ __forceinline__ float rcpf(float x){ return __builtin_amdgcn_rcpf(x); }

// ---------------- K1: fold emb/bias/num path into tables ----------------
// T[dir][v][j] = sum_k emb[v,k]*W[k,j] + b[j] + sum_m num_b[m]*W[128+m,j]   (j < 512)
// U[dir][i][j] = sum_m num_W[i,m]*W[128+m,j]                               (i < 7)
__global__ __launch_bounds__(512) void k1_tables(
    const float* __restrict__ emb, const float* __restrict__ num_W, const float* __restrict__ num_b,
    const float* __restrict__ Wf, const float* __restrict__ bf,
    const float* __restrict__ Wb, const float* __restrict__ bb,
    float* __restrict__ T, float* __restrict__ U)
{
    const int blk = blockIdx.x;
    const int j = threadIdx.x;
    if (blk < 2*VOCABN) {
        const int dir = blk & 1, v = blk >> 1;
        const float* W    = dir ? Wb : Wf;
        const float* bias = dir ? bb : bf;
        float acc = bias[j];
        const float* e = emb + (size_t)v*EMBN;
        #pragma unroll 8
        for (int k=0;k<EMBN;++k) acc = fmaf(e[k], W[(size_t)k*768 + j], acc);
        #pragma unroll
        for (int m=0;m<4;++m)    acc = fmaf(num_b[m], W[(size_t)(EMBN+m)*768 + j], acc);
        T[((size_t)dir*VOCABN + v)*TWOH + j] = acc;
    } else {
        const int dir = blk - 2*VOCABN;
        const float* W = dir ? Wb : Wf;
        #pragma unroll
        for (int i=0;i<NUMIN;++i){
            float acc = 0.f;
            #pragma unroll
            for (int m=0;m<4;++m) acc = fmaf(num_W[i*4+m], W[(size_t)(EMBN+m)*768 + j], acc);
            U[((size_t)dir*8 + i)*TWOH + j] = acc;
        }
    }
}

// ---------------- K2: fused preactivation + fo-pool scan ----------------
// PHASE 0: compute per-wave score partials (h . mu) -> swp. No hc store.
// PHASE 1: recompute scan, accumulate ctx[c] += w[s] * h_s[c] in registers.
// One block per (b, dir); thread j owns channel j. X row prefetched 2 steps
// ahead, T row 1 step ahead to hide L2 gather latency.
template<int PHASE>
__global__ __launch_bounds__(256) void k2_scan(
    const float* __restrict__ X, const float* __restrict__ T, const float* __restrict__ U,
    const float* __restrict__ Mu, const float* __restrict__ w,
    float* __restrict__ swp, float* __restrict__ ctx)
{
    const int b   = blockIdx.x >> 1;
    const int dir = blockIdx.x & 1;
    const int j   = threadIdx.x;
    const float* Td = T + (size_t)dir*VOCABN*TWOH;
    const float* Ud = U + (size_t)dir*8*TWOH;
    float uz[NUMIN], uf[NUMIN];
    #pragma unroll
    for (int i=0;i<NUMIN;++i){ uz[i]=Ud[i*TWOH + j]; uf[i]=Ud[i*TWOH + HDIM + j]; }
    const float mu = Mu[dir*HDIM + j];
    const float* Xb = X + (size_t)b*SN*8;

    __shared__ float wch[256];

    float4 x0a,x0b,x1a,x1b;
    { int sp = dir ? (SN-1) : 0; const float4* p=(const float4*)(Xb+(size_t)sp*8); x0a=p[0]; x0b=p[1]; }
    { int sp = dir ? (SN-2) : 1; const float4* p=(const float4*)(Xb+(size_t)sp*8); x1a=p[0]; x1b=p[1]; }
    int ev0 = (int)x0a.x;
    float tz = Td[ev0*TWOH + j];
    float tf = Td[ev0*TWOH + HDIM + j];
    float h = 0.f;
    float ctxacc = 0.f;
    float* swpp = swp + (size_t)(blockIdx.x*4 + (j>>6))*SN;

    for (int s0=0; s0<SN; s0+=256) {
        if (PHASE==1) {
            __syncthreads();
            wch[j] = w[(size_t)b*SN + s0 + j];
            __syncthreads();
        }
        for (int si=0; si<256; ++si) {
            const int s = s0 + si;
            // prefetch X row for s+2
            int sn2 = s+2; if (sn2 > SN-1) sn2 = SN-1;
            int sp2 = dir ? (SN-1-sn2) : sn2;
            const float4* p2 = (const float4*)(Xb + (size_t)sp2*8);
            float4 x2a = p2[0], x2b = p2[1];
            // prefetch T row for s+1
            int ev1 = (int)x1a.x;
            float tzn = Td[ev1*TWOH + j];
            float tfn = Td[ev1*TWOH + HDIM + j];
            // current step
            float zp = tz, fp = tf;
            zp = fmaf(x0a.y, uz[0], zp); fp = fmaf(x0a.y, uf[0], fp);
            zp = fmaf(x0a.z, uz[1], zp); fp = fmaf(x0a.z, uf[1], fp);
            zp = fmaf(x0a.w, uz[2], zp); fp = fmaf(x0a.w, uf[2], fp);
            zp = fmaf(x0b.x, uz[3], zp); fp = fmaf(x0b.x, uf[3], fp);
            zp = fmaf(x0b.y, uz[4], zp); fp = fmaf(x0b.y, uf[4], fp);
            zp = fmaf(x0b.z, uz[5], zp); fp = fmaf(x0b.z, uf[5], fp);
            zp = fmaf(x0b.w, uz[6], zp); fp = fmaf(x0b.w, uf[6], fp);

            float z = fmaf(-2.f, rcpf(1.f + __expf(2.f*zp)), 1.f); // tanh, overflow-safe
            float f = rcpf(1.f + __expf(-fp));                     // sigmoid, overflow-safe
            h = z + f*(h - z);

            if (PHASE==0) {
                float pr = h * mu;
                #pragma unroll
                for (int o=32;o;o>>=1) pr += __shfl_xor(pr, o, 64);
                if ((j & 63) == 0) swpp[s] = pr;
            } else {
                ctxacc = fmaf(wch[si], h, ctxacc);
            }

            x0a=x1a; x0b=x1b; x1a=x2a; x1b=x2b;
            tz=tzn; tf=tfn;
        }
    }
    if (PHASE==1) ctx[(size_t)b*TWOH + dir*HDIM + j] = ctxacc;
}

// ---------------- K3: softmax over S per batch ----------------
__global__ __launch_bounds__(256) void k3_softmax(const float* __restrict__ swp, float* __restrict__ w)
{
    __shared__ float sc[SN];
    __shared__ float red[4];
    const int b = blockIdx.x, t = threadIdx.x;
    for (int s=t; s<SN; s+=256){
        float acc = 0.f;
        #pragma unroll
        for (int r=0;r<8;++r) acc += swp[((size_t)b*8 + r)*SN + s];
        sc[s] = acc;
    }
    __syncthreads();
    float m = -3.4e38f;
    for (int s=t; s<SN; s+=256) m = fmaxf(m, sc[s]);
    #pragma unroll
    for (int o=32;o;o>>=1) m = fmaxf(m, __shfl_xor(m,o,64));
    if ((t&63)==0) red[t>>6] = m;
    __syncthreads();
    m = fmaxf(fmaxf(red[0],red[1]), fmaxf(red[2],red[3]));
    float zs = 0.f;
    for (int s=t; s<SN; s+=256){
        float e = __expf(sc[s]-m);
        sc[s] = e;
        zs += e;
    }
    #pragma unroll
    for (int o=32;o;o>>=1) zs += __shfl_xor(zs,o,64);
    __syncthreads();
    if ((t&63)==0) red[t>>6] = zs;
    __syncthreads();
    zs = red[0]+red[1]+red[2]+red[3];
    float invz = rcpf(zs);
    for (int s=t; s<SN; s+=256) w[(size_t)b*SN + s] = sc[s]*invz;
}

// ---------------- K5: out[b] = ctx . out_W + out_b ----------------
__global__ __launch_bounds__(512) void k5_out(const float* __restrict__ ctx, const float* __restrict__ out_W,
                                              const float* __restrict__ out_b, float* __restrict__ out)
{
    __shared__ float red[8];
    const int b = blockIdx.x, c = threadIdx.x;
    float p = ctx[(size_t)b*TWOH + c] * out_W[c];
    #pragma unroll
    for (int o=32;o;o>>=1) p += __shfl_xor(p,o,64);
    if ((c&63)==0) red[c>>6] = p;
    __syncthreads();
    if (c==0){
        float t = 0.f;
        #pragma unroll
        for (int r=0;r<8;++r) t += red[r];
        out[b] = t + out_b[0];
    }
}

extern "C" void kernel_launch(void* const* d_in, const int* in_sizes, int n_in,
                              void* d_out, int out_size, void* d_ws, size_t ws_size,
                              hipStream_t stream)
{
    const float* X     = (const float*)d_in[0];
    const float* emb   = (const float*)d_in[1];
    const float* num_W = (const float*)d_in[2];
    const float* num_b = (const float*)d_in[3];
    const float* Wf    = (const float*)d_in[4];
    const float* bf    = (const float*)d_in[5];
    const float* Wb    = (const float*)d_in[6];
    const float* bb    = (const float*)d_in[7];
    const float* Mu    = (const float*)d_in[8];
    const float* out_W = (const float*)d_in[9];
    const float* out_b = (const float*)d_in[10];
    float* out = (float*)d_out;

    float* ws = (float*)d_ws;
    size_t off = 0;
    float* swp  = ws + off; off += (size_t)BN*8*SN;      // 4 MB: per-wave score partials
    float* w    = ws + off; off += (size_t)BN*SN;        // 0.5 MB: softmax weights
    float* T    = ws + off; off += (size_t)2*VOCABN*TWOH;
    float* U    = ws + off; off += (size_t)2*8*TWOH;
    float* ctx  = ws + off; off += (size_t)BN*TWOH;      // 128 KB

    hipLaunchKernelGGL(k1_tables,   dim3(2*VOCABN+2), dim3(512), 0, stream,
                       emb, num_W, num_b, Wf, bf, Wb, bb, T, U);
    hipLaunchKernelGGL(k2_scan<0>,  dim3(BN*2),       dim3(256), 0, stream,
                       X, T, U, Mu, w, swp, ctx);
    hipLaunchKernelGGL(k3_softmax,  dim3(BN),         dim3(256), 0, stream,
                       swp, w);
    hipLaunchKernelGGL(k2_scan<1>,  dim3(BN*2),       dim3(256), 0, stream,
                       X, T, U, Mu, w, swp, ctx);
    hipLaunchKernelGGL(k5_out,      dim3(BN),         dim3(512), 0, stream,
                       ctx, out_W, out_b, out);
}

// Round 3
// 257.175 us; speedup vs baseline: 4.5715x; 4.5715x over previous
//
#include <hip/hip_runtime.h>

#define VOCABN 64
#define EMBN   128
#define HDIM   256
#define NUMIN  7
#define BN     64
#define SN     2048
#define TWOH   512
#define SEG    16
#define SEGLEN 128

__device__ __forceinline__ float rcpf(float x){ return __builtin_amdgcn_rcpf(x); }

// ---------------- K1: fold emb/bias/num path into tables ----------------
// T[dir][v][j] = sum_k emb[v,k]*W[k,j] + b[j] + sum_m num_b[m]*W[128+m,j]   (j < 512)
// U[dir][i][j] = sum_m num_W[i,m]*W[128+m,j]                               (i < 7)
__global__ __launch_bounds__(512) void k1_tables(
    const float* __restrict__ emb, const float* __restrict__ num_W, const float* __restrict__ num_b,
    const float* __restrict__ Wf, const float* __restrict__ bf,
    const float* __restrict__ Wb, const float* __restrict__ bb,
    float* __restrict__ T, float* __restrict__ U)
{
    const int blk = blockIdx.x;
    const int j = threadIdx.x;
    if (blk < 2*VOCABN) {
        const int dir = blk & 1, v = blk >> 1;
        const float* W    = dir ? Wb : Wf;
        const float* bias = dir ? bb : bf;
        float acc = bias[j];
        const float* e = emb + (size_t)v*EMBN;
        #pragma unroll 8
        for (int k=0;k<EMBN;++k) acc = fmaf(e[k], W[(size_t)k*768 + j], acc);
        #pragma unroll
        for (int m=0;m<4;++m)    acc = fmaf(num_b[m], W[(size_t)(EMBN+m)*768 + j], acc);
        T[((size_t)dir*VOCABN + v)*TWOH + j] = acc;
    } else {
        const int dir = blk - 2*VOCABN;
        const float* W = dir ? Wb : Wf;
        #pragma unroll
        for (int i=0;i<NUMIN;++i){
            float acc = 0.f;
            #pragma unroll
            for (int m=0;m<4;++m) acc = fmaf(num_W[i*4+m], W[(size_t)(EMBN+m)*768 + j], acc);
            U[((size_t)dir*8 + i)*TWOH + j] = acc;
        }
    }
}

// ---------------- K2: segmented fo-pool scan ----------------
// MODE 0: per-segment affine coefficients: a = prod(f), c = scan from h0=0.
// MODE 1: scan from hstart, emit per-wave score partials (h . mu).
// MODE 2: scan from hstart, accumulate ctx += w[s] * h.
// Block = (b, dir, seg); thread j owns channel j. X prefetched 2 steps ahead,
// T row 1 step ahead.
template<int MODE>
__global__ __launch_bounds__(256) void k2_scan(
    const float* __restrict__ X, const float* __restrict__ T, const float* __restrict__ U,
    const float* __restrict__ Mu, const float* __restrict__ w,
    const float* __restrict__ hstart,
    float* __restrict__ aArr, float* __restrict__ cArr,
    float* __restrict__ swp, float* __restrict__ ctxp)
{
    const int bid = blockIdx.x;
    const int seg = bid & (SEG-1);
    const int dir = (bid >> 4) & 1;
    const int b   = bid >> 5;
    const int j   = threadIdx.x;
    const size_t segIdx = ((size_t)(b*2+dir)*SEG + seg)*HDIM + j;

    const float* Td = T + (size_t)dir*VOCABN*TWOH;
    const float* Ud = U + (size_t)dir*8*TWOH;
    float uz[NUMIN], uf[NUMIN];
    #pragma unroll
    for (int i=0;i<NUMIN;++i){ uz[i]=Ud[i*TWOH + j]; uf[i]=Ud[i*TWOH + HDIM + j]; }
    const float mu = (MODE==1) ? Mu[dir*HDIM + j] : 0.f;
    const float* Xb = X + (size_t)b*SN*8;

    __shared__ float wch[SEGLEN];
    if (MODE==2) {
        if (j < SEGLEN) wch[j] = w[(size_t)b*SN + seg*SEGLEN + j];
        __syncthreads();
    }

    const int sBeg = seg*SEGLEN;
    float4 x0a,x0b,x1a,x1b;
    { int sp = dir ? (SN-1-sBeg) : sBeg;       const float4* p=(const float4*)(Xb+(size_t)sp*8); x0a=p[0]; x0b=p[1]; }
    { int sp = dir ? (SN-2-sBeg) : (sBeg+1);   const float4* p=(const float4*)(Xb+(size_t)sp*8); x1a=p[0]; x1b=p[1]; }
    int ev0 = (int)x0a.x;
    float tz = Td[ev0*TWOH + j];
    float tf = Td[ev0*TWOH + HDIM + j];

    float h = (MODE==0) ? 0.f : hstart[segIdx];
    float aacc = 1.f;
    float ctxacc = 0.f;
    float* swpp = swp + (size_t)(b*8 + dir*4 + (j>>6))*SN;

    for (int si=0; si<SEGLEN; ++si) {
        const int s = sBeg + si;
        // prefetch X row for scan position s+2 (clamped to sequence end)
        int sn2 = s+2; if (sn2 > SN-1) sn2 = SN-1;
        int sp2 = dir ? (SN-1-sn2) : sn2;
        const float4* p2 = (const float4*)(Xb + (size_t)sp2*8);
        float4 x2a = p2[0], x2b = p2[1];
        // prefetch T row for s+1
        int ev1 = (int)x1a.x;
        float tzn = Td[ev1*TWOH + j];
        float tfn = Td[ev1*TWOH + HDIM + j];
        // current step
        float zp = tz, fp = tf;
        zp = fmaf(x0a.y, uz[0], zp); fp = fmaf(x0a.y, uf[0], fp);
        zp = fmaf(x0a.z, uz[1], zp); fp = fmaf(x0a.z, uf[1], fp);
        zp = fmaf(x0a.w, uz[2], zp); fp = fmaf(x0a.w, uf[2], fp);
        zp = fmaf(x0b.x, uz[3], zp); fp = fmaf(x0b.x, uf[3], fp);
        zp = fmaf(x0b.y, uz[4], zp); fp = fmaf(x0b.y, uf[4], fp);
        zp = fmaf(x0b.z, uz[5], zp); fp = fmaf(x0b.z, uf[5], fp);
        zp = fmaf(x0b.w, uz[6], zp); fp = fmaf(x0b.w, uf[6], fp);

        float z = fmaf(-2.f, rcpf(1.f + __expf(2.f*zp)), 1.f); // tanh, overflow-safe
        float f = rcpf(1.f + __expf(-fp));                     // sigmoid, overflow-safe
        if (MODE==0) aacc *= f;
        h = z + f*(h - z);

        if (MODE==1) {
            float pr = h * mu;
            #pragma unroll
            for (int o=32;o;o>>=1) pr += __shfl_xor(pr, o, 64);
            if ((j & 63) == 0) swpp[s] = pr;
        } else if (MODE==2) {
            ctxacc = fmaf(wch[si], h, ctxacc);
        }

        x0a=x1a; x0b=x1b; x1a=x2a; x1b=x2b;
        tz=tzn; tf=tfn;
    }
    if (MODE==0) { aArr[segIdx] = aacc; cArr[segIdx] = h; }
    if (MODE==2) { ctxp[segIdx] = ctxacc; }
}

// ---------------- compose: sequential over segments: hstart[seg] = h; h = a*h + c ----------------
__global__ __launch_bounds__(256) void k_compose(const float* __restrict__ aArr, const float* __restrict__ cArr,
                                                 float* __restrict__ hstart)
{
    const int bd = blockIdx.x;   // b*2 + dir
    const int j  = threadIdx.x;
    float h = 0.f;
    #pragma unroll
    for (int seg=0; seg<SEG; ++seg){
        const size_t idx = ((size_t)bd*SEG + seg)*HDIM + j;
        hstart[idx] = h;
        h = fmaf(aArr[idx], h, cArr[idx]);
    }
}

// ---------------- K3: softmax over S per batch ----------------
__global__ __launch_bounds__(256) void k3_softmax(const float* __restrict__ swp, float* __restrict__ w)
{
    __shared__ float sc[SN];
    __shared__ float red[4];
    const int b = blockIdx.x, t = threadIdx.x;
    for (int s=t; s<SN; s+=256){
        float acc = 0.f;
        #pragma unroll
        for (int r=0;r<8;++r) acc += swp[((size_t)b*8 + r)*SN + s];
        sc[s] = acc;
    }
    __syncthreads();
    float m = -3.4e38f;
    for (int s=t; s<SN; s+=256) m = fmaxf(m, sc[s]);
    #pragma unroll
    for (int o=32;o;o>>=1) m = fmaxf(m, __shfl_xor(m,o,64));
    if ((t&63)==0) red[t>>6] = m;
    __syncthreads();
    m = fmaxf(fmaxf(red[0],red[1]), fmaxf(red[2],red[3]));
    float zs = 0.f;
    for (int s=t; s<SN; s+=256){
        float e = __expf(sc[s]-m);
        sc[s] = e;
        zs += e;
    }
    #pragma unroll
    for (int o=32;o;o>>=1) zs += __shfl_xor(zs,o,64);
    __syncthreads();
    if ((t&63)==0) red[t>>6] = zs;
    __syncthreads();
    zs = red[0]+red[1]+red[2]+red[3];
    float invz = rcpf(zs);
    for (int s=t; s<SN; s+=256) w[(size_t)b*SN + s] = sc[s]*invz;
}

// ---------------- K5: out[b] = (sum_seg ctxp) . out_W + out_b ----------------
__global__ __launch_bounds__(512) void k5_out(const float* __restrict__ ctxp, const float* __restrict__ out_W,
                                              const float* __restrict__ out_b, float* __restrict__ out)
{
    __shared__ float red[8];
    const int b = blockIdx.x, c = threadIdx.x;
    const int dir = c >> 8, j = c & (HDIM-1);
    float acc = 0.f;
    #pragma unroll
    for (int seg=0; seg<SEG; ++seg)
        acc += ctxp[((size_t)(b*2+dir)*SEG + seg)*HDIM + j];
    float p = acc * out_W[c];
    #pragma unroll
    for (int o=32;o;o>>=1) p += __shfl_xor(p,o,64);
    if ((c&63)==0) red[c>>6] = p;
    __syncthreads();
    if (c==0){
        float t = 0.f;
        #pragma unroll
        for (int r=0;r<8;++r) t += red[r];
        out[b] = t + out_b[0];
    }
}

extern "C" void kernel_launch(void* const* d_in, const int* in_sizes, int n_in,
                              void* d_out, int out_size, void* d_ws, size_t ws_size,
                              hipStream_t stream)
{
    const float* X     = (const float*)d_in[0];
    const float* emb   = (const float*)d_in[1];
    const float* num_W = (const float*)d_in[2];
    const float* num_b = (const float*)d_in[3];
    const float* Wf    = (const float*)d_in[4];
    const float* bf    = (const float*)d_in[5];
    const float* Wb    = (const float*)d_in[6];
    const float* bb    = (const float*)d_in[7];
    const float* Mu    = (const float*)d_in[8];
    const float* out_W = (const float*)d_in[9];
    const float* out_b = (const float*)d_in[10];
    float* out = (float*)d_out;

    float* ws = (float*)d_ws;
    size_t off = 0;
    float* swp   = ws + off; off += (size_t)BN*8*SN;           // 4 MB
    float* w     = ws + off; off += (size_t)BN*SN;             // 0.5 MB
    float* T     = ws + off; off += (size_t)2*VOCABN*TWOH;
    float* U     = ws + off; off += (size_t)2*8*TWOH;
    float* aArr  = ws + off; off += (size_t)BN*2*SEG*HDIM;     // 2 MB
    float* cArr  = ws + off; off += (size_t)BN*2*SEG*HDIM;     // 2 MB
    float* hstart= ws + off; off += (size_t)BN*2*SEG*HDIM;     // 2 MB
    float* ctxp  = ws + off; off += (size_t)BN*2*SEG*HDIM;     // 2 MB

    hipLaunchKernelGGL(k1_tables,   dim3(2*VOCABN+2),  dim3(512), 0, stream,
                       emb, num_W, num_b, Wf, bf, Wb, bb, T, U);
    hipLaunchKernelGGL(k2_scan<0>,  dim3(BN*2*SEG),    dim3(256), 0, stream,
                       X, T, U, Mu, w, hstart, aArr, cArr, swp, ctxp);
    hipLaunchKernelGGL(k_compose,   dim3(BN*2),        dim3(256), 0, stream,
                       aArr, cArr, hstart);
    hipLaunchKernelGGL(k2_scan<1>,  dim3(BN*2*SEG),    dim3(256), 0, stream,
                       X, T, U, Mu, w, hstart, aArr, cArr, swp, ctxp);
    hipLaunchKernelGGL(k3_softmax,  dim3(BN),          dim3(256), 0, stream,
                       swp, w);
    hipLaunchKernelGGL(k2_scan<2>,  dim3(BN*2*SEG),    dim3(256), 0, stream,
                       X, T, U, Mu, w, hstart, aArr, cArr, swp, ctxp);
    hipLaunchKernelGGL(k5_out,      dim3(BN),          dim3(512), 0, stream,
                       ctxp, out_W, out_b, out);
}

// Round 4
// 218.066 us; speedup vs baseline: 5.3914x; 1.1793x over previous
//
#include <hip/hip_runtime.h>

#define VOCABN 64
#define EMBN   128
#define HDIM   256
#define NUMIN  7
#define BN     64
#define SN     2048
#define TWOH   512
#define SEG    16
#define SEGLEN 128

__device__ __forceinline__ float rcpf(float x){ return __builtin_amdgcn_rcpf(x); }

__device__ __forceinline__ float fast_exp2(float x){
#if __has_builtin(__builtin_amdgcn_exp2f)
    return __builtin_amdgcn_exp2f(x);
#else
    return exp2f(x);
#endif
}

__device__ __forceinline__ float2 pk_fma(float2 a, float2 b, float2 c){
    float2 d;
    asm("v_pk_fma_f32 %0, %1, %2, %3" : "=v"(d) : "v"(a), "v"(b), "v"(c));
    return d;
}
__device__ __forceinline__ float2 pk_mul(float2 a, float2 b){
    float2 d;
    asm("v_pk_mul_f32 %0, %1, %2" : "=v"(d) : "v"(a), "v"(b));
    return d;
}

// 64-lane sum via DPP (LLVM atomic-optimizer sequence); result valid in lane 63.
__device__ __forceinline__ float waveRedDpp(float x){
    x += __int_as_float(__builtin_amdgcn_update_dpp(0, __float_as_int(x), 0x111, 0xf, 0xf, false)); // row_shr:1
    x += __int_as_float(__builtin_amdgcn_update_dpp(0, __float_as_int(x), 0x112, 0xf, 0xf, false)); // row_shr:2
    x += __int_as_float(__builtin_amdgcn_update_dpp(0, __float_as_int(x), 0x114, 0xf, 0xf, false)); // row_shr:4
    x += __int_as_float(__builtin_amdgcn_update_dpp(0, __float_as_int(x), 0x118, 0xf, 0xf, false)); // row_shr:8
    x += __int_as_float(__builtin_amdgcn_update_dpp(0, __float_as_int(x), 0x142, 0xa, 0xf, false)); // row_bcast:15
    x += __int_as_float(__builtin_amdgcn_update_dpp(0, __float_as_int(x), 0x143, 0xc, 0xf, false)); // row_bcast:31
    return x;
}

// ---------------- K1: fold emb/bias/num path into INTERLEAVED tables ----------------
// T[(dir,v,j)] = float2(z-col j, f-col j+256); U[(dir,i,j)] likewise.
__global__ __launch_bounds__(512) void k1_tables(
    const float* __restrict__ emb, const float* __restrict__ num_W, const float* __restrict__ num_b,
    const float* __restrict__ Wf, const float* __restrict__ bf,
    const float* __restrict__ Wb, const float* __restrict__ bb,
    float* __restrict__ T, float* __restrict__ U)
{
    const int blk = blockIdx.x;
    const int c = threadIdx.x;
    const int j = c & (HDIM-1);
    const int g = c >> 8;               // 0 -> z gate, 1 -> f gate
    const int col = g*HDIM + j;
    if (blk < 2*VOCABN) {
        const int dir = blk & 1, v = blk >> 1;
        const float* W    = dir ? Wb : Wf;
        const float* bias = dir ? bb : bf;
        float acc = bias[col];
        const float* e = emb + (size_t)v*EMBN;
        #pragma unroll 8
        for (int k=0;k<EMBN;++k) acc = fmaf(e[k], W[(size_t)k*768 + col], acc);
        #pragma unroll
        for (int m=0;m<4;++m)    acc = fmaf(num_b[m], W[(size_t)(EMBN+m)*768 + col], acc);
        T[(((size_t)dir*VOCABN + v)*HDIM + j)*2 + g] = acc;
    } else {
        const int dir = blk - 2*VOCABN;
        const float* W = dir ? Wb : Wf;
        #pragma unroll
        for (int i=0;i<NUMIN;++i){
            float acc = 0.f;
            #pragma unroll
            for (int m=0;m<4;++m) acc = fmaf(num_W[i*4+m], W[(size_t)(EMBN+m)*768 + col], acc);
            U[(((size_t)dir*8 + i)*HDIM + j)*2 + g] = acc;
        }
    }
}

// ---------------- K2: segmented fo-pool scan (packed math) ----------------
// MODE 0: per-segment affine coefficients a=prod(f), c=scan from 0.
// MODE 1: scan from hstart, per-wave score partials via DPP reduce.
// MODE 2: scan from hstart, ctx += w[s]*h.
// Block=(b,dir,seg), thread j owns channel j; (zp,fp) packed in a VGPR pair.
template<int MODE>
__global__ __launch_bounds__(256) void k2_scan(
    const float* __restrict__ X, const float* __restrict__ T, const float* __restrict__ U,
    const float* __restrict__ Mu, const float* __restrict__ w,
    const float* __restrict__ hstart,
    float* __restrict__ aArr, float* __restrict__ cArr,
    float* __restrict__ swp, float* __restrict__ ctxp)
{
    const int bid = blockIdx.x;
    const int seg = bid & (SEG-1);
    const int dir = (bid >> 4) & 1;
    const int b   = bid >> 5;
    const int j   = threadIdx.x;
    const size_t segIdx = ((size_t)(b*2+dir)*SEG + seg)*HDIM + j;

    const float2* Td2 = (const float2*)T + (size_t)dir*VOCABN*HDIM;
    const float2* Ud2 = (const float2*)U + (size_t)dir*8*HDIM;
    float2 u0 = Ud2[0*HDIM+j], u1 = Ud2[1*HDIM+j], u2 = Ud2[2*HDIM+j],
           u3 = Ud2[3*HDIM+j], u4 = Ud2[4*HDIM+j], u5 = Ud2[5*HDIM+j],
           u6 = Ud2[6*HDIM+j];
    const float mu = (MODE==1) ? Mu[dir*HDIM + j] : 0.f;
    const float* Xb = X + (size_t)b*SN*8;

    // LDS: per-step row = [n0n0 n1n1 n2n2 n3n3 n4n4 n5n5 n6n6 evbyteoff pad] (16 floats)
    __shared__ float4 xlds[SEGLEN][4];
    __shared__ float wch[SEGLEN];

    const int sBeg = seg*SEGLEN;
    {   // staging: 2 threads per row
        const int r = j >> 1, half = j & 1;
        const int gp = dir ? (SN-1-(sBeg+r)) : (sBeg+r);
        const float4 v4 = *(const float4*)(Xb + (size_t)gp*8 + half*4);
        float2* rowp = (float2*)&xlds[r][0];
        if (half==0){
            rowp[0] = make_float2(v4.y, v4.y);
            rowp[1] = make_float2(v4.z, v4.z);
            rowp[2] = make_float2(v4.w, v4.w);
            ((float*)rowp)[14] = __int_as_float((int)v4.x * (HDIM*8)); // byte offset of T row
        } else {
            rowp[3] = make_float2(v4.x, v4.x);
            rowp[4] = make_float2(v4.y, v4.y);
            rowp[5] = make_float2(v4.z, v4.z);
            rowp[6] = make_float2(v4.w, v4.w);
        }
        if (MODE==2 && j < SEGLEN) wch[j] = w[(size_t)b*SN + sBeg + j];
    }
    __syncthreads();

    float h = (MODE==0) ? 0.f : hstart[segIdx];
    float aacc = 1.f;
    float ctxacc = 0.f;
    float* swpp = swp + (size_t)(b*8 + dir*4 + (j>>6))*SN + sBeg;

    const int j8 = j*8;
    float4 xd = xlds[0][3];
    float2 tcur = *(const float2*)((const char*)Td2 + (__float_as_int(xd.z) + j8));
    const float2 ecst = make_float2(2.8853900818f, -1.4426950409f); // 2*log2(e), -log2(e)

    #pragma unroll 4
    for (int si=0; si<SEGLEN; ++si){
        const int sn = (si+1 < SEGLEN) ? si+1 : si;
        const float4 xa  = xlds[si][0];
        const float4 xb_ = xlds[si][1];
        const float4 xc  = xlds[si][2];
        const float4 xdn = xlds[sn][3];
        const float2 tnext = *(const float2*)((const char*)Td2 + (__float_as_int(xdn.z) + j8));

        float2 zf = tcur;
        zf = pk_fma(make_float2(xa.x ,xa.y ), u0, zf);
        zf = pk_fma(make_float2(xa.z ,xa.w ), u1, zf);
        zf = pk_fma(make_float2(xb_.x,xb_.y), u2, zf);
        zf = pk_fma(make_float2(xb_.z,xb_.w), u3, zf);
        zf = pk_fma(make_float2(xc.x ,xc.y ), u4, zf);
        zf = pk_fma(make_float2(xc.z ,xc.w ), u5, zf);
        zf = pk_fma(make_float2(xd.x ,xd.y ), u6, zf);

        const float2 ex = pk_mul(zf, ecst);           // (2*log2e*zp, -log2e*fp)
        const float rz = rcpf(1.f + fast_exp2(ex.x)); // 1/(1+e^{2zp})
        const float f  = rcpf(1.f + fast_exp2(ex.y)); // sigmoid(fp)
        const float z  = fmaf(-2.f, rz, 1.f);         // tanh(zp)
        if (MODE==0) aacc *= f;
        h = z + f*(h - z);

        if (MODE==1){
            float pr = waveRedDpp(h*mu);
            if ((j & 63) == 63) swpp[si] = pr;
        } else if (MODE==2){
            ctxacc = fmaf(wch[si], h, ctxacc);
        }
        tcur = tnext; xd = xdn;
    }
    if (MODE==0){ aArr[segIdx] = aacc; cArr[segIdx] = h; }
    if (MODE==2){ ctxp[segIdx] = ctxacc; }
}

// ---------------- compose: hstart[seg] = h; h = a*h + c ----------------
__global__ __launch_bounds__(256) void k_compose(const float* __restrict__ aArr, const float* __restrict__ cArr,
                                                 float* __restrict__ hstart)
{
    const int bd = blockIdx.x;   // b*2 + dir
    const int j  = threadIdx.x;
    float h = 0.f;
    #pragma unroll
    for (int seg=0; seg<SEG; ++seg){
        const size_t idx = ((size_t)bd*SEG + seg)*HDIM + j;
        hstart[idx] = h;
        h = fmaf(aArr[idx], h, cArr[idx]);
    }
}

// ---------------- K3: softmax over S per batch ----------------
__global__ __launch_bounds__(256) void k3_softmax(const float* __restrict__ swp, float* __restrict__ w)
{
    __shared__ float sc[SN];
    __shared__ float red[4];
    const int b = blockIdx.x, t = threadIdx.x;
    for (int s=t; s<SN; s+=256){
        float acc = 0.f;
        #pragma unroll
        for (int r=0;r<8;++r) acc += swp[((size_t)b*8 + r)*SN + s];
        sc[s] = acc;
    }
    __syncthreads();
    float m = -3.4e38f;
    for (int s=t; s<SN; s+=256) m = fmaxf(m, sc[s]);
    #pragma unroll
    for (int o=32;o;o>>=1) m = fmaxf(m, __shfl_xor(m,o,64));
    if ((t&63)==0) red[t>>6] = m;
    __syncthreads();
    m = fmaxf(fmaxf(red[0],red[1]), fmaxf(red[2],red[3]));
    float zs = 0.f;
    for (int s=t; s<SN; s+=256){
        float e = __expf(sc[s]-m);
        sc[s] = e;
        zs += e;
    }
    #pragma unroll
    for (int o=32;o;o>>=1) zs += __shfl_xor(zs,o,64);
    __syncthreads();
    if ((t&63)==0) red[t>>6] = zs;
    __syncthreads();
    zs = red[0]+red[1]+red[2]+red[3];
    float invz = rcpf(zs);
    for (int s=t; s<SN; s+=256) w[(size_t)b*SN + s] = sc[s]*invz;
}

// ---------------- K5: out[b] = (sum_seg ctxp) . out_W + out_b ----------------
__global__ __launch_bounds__(512) void k5_out(const float* __restrict__ ctxp, const float* __restrict__ out_W,
                                              const float* __restrict__ out_b, float* __restrict__ out)
{
    __shared__ float red[8];
    const int b = blockIdx.x, c = threadIdx.x;
    const int dir = c >> 8, j = c & (HDIM-1);
    float acc = 0.f;
    #pragma unroll
    for (int seg=0; seg<SEG; ++seg)
        acc += ctxp[((size_t)(b*2+dir)*SEG + seg)*HDIM + j];
    float p = acc * out_W[c];
    #pragma unroll
    for (int o=32;o;o>>=1) p += __shfl_xor(p,o,64);
    if ((c&63)==0) red[c>>6] = p;
    __syncthreads();
    if (c==0){
        float t = 0.f;
        #pragma unroll
        for (int r=0;r<8;++r) t += red[r];
        out[b] = t + out_b[0];
    }
}

extern "C" void kernel_launch(void* const* d_in, const int* in_sizes, int n_in,
                              void* d_out, int out_size, void* d_ws, size_t ws_size,
                              hipStream_t stream)
{
    const float* X     = (const float*)d_in[0];
    const float* emb   = (const float*)d_in[1];
    const float* num_W = (const float*)d_in[2];
    const float* num_b = (const float*)d_in[3];
    const float* Wf    = (const float*)d_in[4];
    const float* bf    = (const float*)d_in[5];
    const float* Wb    = (const float*)d_in[6];
    const float* bb    = (const float*)d_in[7];
    const float* Mu    = (const float*)d_in[8];
    const float* out_W = (const float*)d_in[9];
    const float* out_b = (const float*)d_in[10];
    float* out = (float*)d_out;

    float* ws = (float*)d_ws;
    size_t off = 0;
    float* swp   = ws + off; off += (size_t)BN*8*SN;           // 4 MB
    float* w     = ws + off; off += (size_t)BN*SN;             // 0.5 MB
    float* T     = ws + off; off += (size_t)2*VOCABN*TWOH;     // interleaved
    float* U     = ws + off; off += (size_t)2*8*TWOH;          // interleaved
    float* aArr  = ws + off; off += (size_t)BN*2*SEG*HDIM;     // 2 MB
    float* cArr  = ws + off; off += (size_t)BN*2*SEG*HDIM;     // 2 MB
    float* hstart= ws + off; off += (size_t)BN*2*SEG*HDIM;     // 2 MB
    float* ctxp  = ws + off; off += (size_t)BN*2*SEG*HDIM;     // 2 MB

    hipLaunchKernelGGL(k1_tables,   dim3(2*VOCABN+2),  dim3(512), 0, stream,
                       emb, num_W, num_b, Wf, bf, Wb, bb, T, U);
    hipLaunchKernelGGL(k2_scan<0>,  dim3(BN*2*SEG),    dim3(256), 0, stream,
                       X, T, U, Mu, w, hstart, aArr, cArr, swp, ctxp);
    hipLaunchKernelGGL(k_compose,   dim3(BN*2),        dim3(256), 0, stream,
                       aArr, cArr, hstart);
    hipLaunchKernelGGL(k2_scan<1>,  dim3(BN*2*SEG),    dim3(256), 0, stream,
                       X, T, U, Mu, w, hstart, aArr, cArr, swp, ctxp);
    hipLaunchKernelGGL(k3_softmax,  dim3(BN),          dim3(256), 0, stream,
                       swp, w);
    hipLaunchKernelGGL(k2_scan<2>,  dim3(BN*2*SEG),    dim3(256), 0, stream,
                       X, T, U, Mu, w, hstart, aArr, cArr, swp, ctxp);
    hipLaunchKernelGGL(k5_out,      dim3(BN),          dim3(512), 0, stream,
                       ctxp, out_W, out_b, out);
}

// Round 5
// 208.175 us; speedup vs baseline: 5.6476x; 1.0475x over previous
//
#include <hip/hip_runtime.h>

#define VOCABN 64
#define EMBN   128
#define HDIM   256
#define NUMIN  7
#define BN     64
#define SN     2048
#define TWOH   512
#define SEG    16
#define SEGLEN 128

__device__ __forceinline__ float rcpf(float x){ return __builtin_amdgcn_rcpf(x); }

__device__ __forceinline__ float fast_exp2(float x){
#if __has_builtin(__builtin_amdgcn_exp2f)
    return __builtin_amdgcn_exp2f(x);
#else
    return exp2f(x);
#endif
}

// v_pk_fma_f32 with src0 broadcast from LO half (result.lo and .hi both use src0.lo)
__device__ __forceinline__ float2 pk_fma_blo(float2 a, float2 b, float2 c){
    float2 d;
    asm("v_pk_fma_f32 %0, %1, %2, %3 op_sel_hi:[0,1,1]" : "=v"(d) : "v"(a), "v"(b), "v"(c));
    return d;
}
// v_pk_fma_f32 with src0 broadcast from HI half
__device__ __forceinline__ float2 pk_fma_bhi(float2 a, float2 b, float2 c){
    float2 d;
    asm("v_pk_fma_f32 %0, %1, %2, %3 op_sel:[1,0,0] op_sel_hi:[1,1,1]" : "=v"(d) : "v"(a), "v"(b), "v"(c));
    return d;
}
__device__ __forceinline__ float2 pk_mul(float2 a, float2 b){
    float2 d;
    asm("v_pk_mul_f32 %0, %1, %2" : "=v"(d) : "v"(a), "v"(b));
    return d;
}

// 64-lane sum via DPP; result valid in lane 63.
__device__ __forceinline__ float waveRedDpp(float x){
    x += __int_as_float(__builtin_amdgcn_update_dpp(0, __float_as_int(x), 0x111, 0xf, 0xf, false)); // row_shr:1
    x += __int_as_float(__builtin_amdgcn_update_dpp(0, __float_as_int(x), 0x112, 0xf, 0xf, false)); // row_shr:2
    x += __int_as_float(__builtin_amdgcn_update_dpp(0, __float_as_int(x), 0x114, 0xf, 0xf, false)); // row_shr:4
    x += __int_as_float(__builtin_amdgcn_update_dpp(0, __float_as_int(x), 0x118, 0xf, 0xf, false)); // row_shr:8
    x += __int_as_float(__builtin_amdgcn_update_dpp(0, __float_as_int(x), 0x142, 0xa, 0xf, false)); // row_bcast:15
    x += __int_as_float(__builtin_amdgcn_update_dpp(0, __float_as_int(x), 0x143, 0xc, 0xf, false)); // row_bcast:31
    return x;
}

// ---------------- K1: fold emb/bias/num path into INTERLEAVED tables ----------------
// T[(dir,v,j)] = float2(z-col j, f-col j+256); U[(dir,i,j)] likewise.
__global__ __launch_bounds__(512) void k1_tables(
    const float* __restrict__ emb, const float* __restrict__ num_W, const float* __restrict__ num_b,
    const float* __restrict__ Wf, const float* __restrict__ bf,
    const float* __restrict__ Wb, const float* __restrict__ bb,
    float* __restrict__ T, float* __restrict__ U)
{
    const int blk = blockIdx.x;
    const int c = threadIdx.x;
    const int j = c & (HDIM-1);
    const int g = c >> 8;               // 0 -> z gate, 1 -> f gate
    const int col = g*HDIM + j;
    if (blk < 2*VOCABN) {
        const int dir = blk & 1, v = blk >> 1;
        const float* W    = dir ? Wb : Wf;
        const float* bias = dir ? bb : bf;
        float acc = bias[col];
        const float* e = emb + (size_t)v*EMBN;
        #pragma unroll 8
        for (int k=0;k<EMBN;++k) acc = fmaf(e[k], W[(size_t)k*768 + col], acc);
        #pragma unroll
        for (int m=0;m<4;++m)    acc = fmaf(num_b[m], W[(size_t)(EMBN+m)*768 + col], acc);
        T[(((size_t)dir*VOCABN + v)*HDIM + j)*2 + g] = acc;
    } else {
        const int dir = blk - 2*VOCABN;
        const float* W = dir ? Wb : Wf;
        #pragma unroll
        for (int i=0;i<NUMIN;++i){
            float acc = 0.f;
            #pragma unroll
            for (int m=0;m<4;++m) acc = fmaf(num_W[i*4+m], W[(size_t)(EMBN+m)*768 + col], acc);
            U[(((size_t)dir*8 + i)*HDIM + j)*2 + g] = acc;
        }
    }
}

// ---------------- K2: segmented fo-pool scan (packed math, lean LDS) ----------------
// MODE 0: per-segment affine coefficients a=prod(f), c=scan from 0.
// MODE 1: scan from hstart, per-wave score partials via DPP reduce.
// MODE 2: scan from hstart, ctx += w[s]*h.
// Block=(b,dir,seg), thread j owns channel j; (zp,fp) packed in a VGPR pair.
// X rows staged raw (32B: [evByteOff, n0..n6]); pk_fma op_sel broadcasts n_i.
template<int MODE>
__global__ __launch_bounds__(256) void k2_scan(
    const float* __restrict__ X, const float* __restrict__ T, const float* __restrict__ U,
    const float* __restrict__ Mu, const float* __restrict__ w,
    const float* __restrict__ hstart,
    float* __restrict__ aArr, float* __restrict__ cArr,
    float* __restrict__ swp, float* __restrict__ ctxp)
{
    const int bid = blockIdx.x;
    const int seg = bid & (SEG-1);
    const int dir = (bid >> 4) & 1;
    const int b   = bid >> 5;
    const int j   = threadIdx.x;
    const size_t segIdx = ((size_t)(b*2+dir)*SEG + seg)*HDIM + j;

    const float2* Td2 = (const float2*)T + (size_t)dir*VOCABN*HDIM;
    const float2* Ud2 = (const float2*)U + (size_t)dir*8*HDIM;
    float2 u0 = Ud2[0*HDIM+j], u1 = Ud2[1*HDIM+j], u2 = Ud2[2*HDIM+j],
           u3 = Ud2[3*HDIM+j], u4 = Ud2[4*HDIM+j], u5 = Ud2[5*HDIM+j],
           u6 = Ud2[6*HDIM+j];
    const float mu = (MODE==1) ? Mu[dir*HDIM + j] : 0.f;
    const float* Xb = X + (size_t)b*SN*8;

    __shared__ float4 xlds[SEGLEN][2];   // raw X row: [evByteOff n0 n1 n2][n3 n4 n5 n6]
    __shared__ float wch[SEGLEN];

    const int sBeg = seg*SEGLEN;
    {   // staging: thread j stores one contiguous 16B chunk -> conflict-free
        const int r = j >> 1, half = j & 1;
        const int gp = dir ? (SN-1-(sBeg+r)) : (sBeg+r);
        float4 v4 = *(const float4*)(Xb + (size_t)gp*8 + half*4);
        if (half==0) v4.x = __int_as_float((int)v4.x * (HDIM*8)); // T-row byte offset
        xlds[r][half] = v4;
        if (MODE==2 && j < SEGLEN) wch[j] = w[(size_t)b*SN + sBeg + j];
    }
    __syncthreads();

    float h = (MODE==0) ? 0.f : hstart[segIdx];
    float aacc = 1.f;
    float ctxacc = 0.f;
    float* swpp = swp + (size_t)(b*8 + dir*4 + (j>>6))*SN + sBeg;

    const int j8 = j*8;
    float4 A  = xlds[0][0];
    float4 B4 = xlds[0][1];
    float2 tcur = *(const float2*)((const char*)Td2 + (__float_as_int(A.x) + j8));
    const float2 ecst = make_float2(2.8853900818f, -1.4426950409f); // 2*log2(e), -log2(e)

    #pragma unroll 4
    for (int si=0; si<SEGLEN; ++si){
        const int sn = (si+1 < SEGLEN) ? si+1 : si;
        const float4 An = xlds[sn][0];
        const float4 Bn = xlds[sn][1];
        const float2 tnext = *(const float2*)((const char*)Td2 + (__float_as_int(An.x) + j8));

        float2 zf = tcur;
        zf = pk_fma_bhi(make_float2(A.x ,A.y ), u0, zf);  // n0 = A.y
        zf = pk_fma_blo(make_float2(A.z ,A.w ), u1, zf);  // n1 = A.z
        zf = pk_fma_bhi(make_float2(A.z ,A.w ), u2, zf);  // n2 = A.w
        zf = pk_fma_blo(make_float2(B4.x,B4.y), u3, zf);  // n3
        zf = pk_fma_bhi(make_float2(B4.x,B4.y), u4, zf);  // n4
        zf = pk_fma_blo(make_float2(B4.z,B4.w), u5, zf);  // n5
        zf = pk_fma_bhi(make_float2(B4.z,B4.w), u6, zf);  // n6

        const float2 ex = pk_mul(zf, ecst);           // (2*log2e*zp, -log2e*fp)
        const float rz = rcpf(1.f + fast_exp2(ex.x)); // 1/(1+e^{2zp})
        const float f  = rcpf(1.f + fast_exp2(ex.y)); // sigmoid(fp)
        const float z  = fmaf(-2.f, rz, 1.f);         // tanh(zp)
        if (MODE==0) aacc *= f;
        h = z + f*(h - z);

        if (MODE==1){
            float pr = waveRedDpp(h*mu);
            if ((j & 63) == 63) swpp[si] = pr;
        } else if (MODE==2){
            ctxacc = fmaf(wch[si], h, ctxacc);
        }
        A = An; B4 = Bn; tcur = tnext;
    }
    if (MODE==0){ aArr[segIdx] = aacc; cArr[segIdx] = h; }
    if (MODE==2){ ctxp[segIdx] = ctxacc; }
}

// ---------------- compose: hstart[seg] = h; h = a*h + c ----------------
__global__ __launch_bounds__(256) void k_compose(const float* __restrict__ aArr, const float* __restrict__ cArr,
                                                 float* __restrict__ hstart)
{
    const int bd = blockIdx.x;   // b*2 + dir
    const int j  = threadIdx.x;
    float h = 0.f;
    #pragma unroll
    for (int seg=0; seg<SEG; ++seg){
        const size_t idx = ((size_t)bd*SEG + seg)*HDIM + j;
        hstart[idx] = h;
        h = fmaf(aArr[idx], h, cArr[idx]);
    }
}

// ---------------- K3: softmax over S per batch ----------------
__global__ __launch_bounds__(256) void k3_softmax(const float* __restrict__ swp, float* __restrict__ w)
{
    __shared__ float sc[SN];
    __shared__ float red[4];
    const int b = blockIdx.x, t = threadIdx.x;
    for (int s=t; s<SN; s+=256){
        float acc = 0.f;
        #pragma unroll
        for (int r=0;r<8;++r) acc += swp[((size_t)b*8 + r)*SN + s];
        sc[s] = acc;
    }
    __syncthreads();
    float m = -3.4e38f;
    for (int s=t; s<SN; s+=256) m = fmaxf(m, sc[s]);
    #pragma unroll
    for (int o=32;o;o>>=1) m = fmaxf(m, __shfl_xor(m,o,64));
    if ((t&63)==0) red[t>>6] = m;
    __syncthreads();
    m = fmaxf(fmaxf(red[0],red[1]), fmaxf(red[2],red[3]));
    float zs = 0.f;
    for (int s=t; s<SN; s+=256){
        float e = __expf(sc[s]-m);
        sc[s] = e;
        zs += e;
    }
    #pragma unroll
    for (int o=32;o;o>>=1) zs += __shfl_xor(zs,o,64);
    __syncthreads();
    if ((t&63)==0) red[t>>6] = zs;
    __syncthreads();
    zs = red[0]+red[1]+red[2]+red[3];
    float invz = rcpf(zs);
    for (int s=t; s<SN; s+=256) w[(size_t)b*SN + s] = sc[s]*invz;
}

// ---------------- K5: out[b] = (sum_seg ctxp) . out_W + out_b ----------------
__global__ __launch_bounds__(512) void k5_out(const float* __restrict__ ctxp, const float* __restrict__ out_W,
                                              const float* __restrict__ out_b, float* __restrict__ out)
{
    __shared__ float red[8];
    const int b = blockIdx.x, c = threadIdx.x;
    const int dir = c >> 8, j = c & (HDIM-1);
    float acc = 0.f;
    #pragma unroll
    for (int seg=0; seg<SEG; ++seg)
        acc += ctxp[((size_t)(b*2+dir)*SEG + seg)*HDIM + j];
    float p = acc * out_W[c];
    #pragma unroll
    for (int o=32;o;o>>=1) p += __shfl_xor(p,o,64);
    if ((c&63)==0) red[c>>6] = p;
    __syncthreads();
    if (c==0){
        float t = 0.f;
        #pragma unroll
        for (int r=0;r<8;++r) t += red[r];
        out[b] = t + out_b[0];
    }
}

extern "C" void kernel_launch(void* const* d_in, const int* in_sizes, int n_in,
                              void* d_out, int out_size, void* d_ws, size_t ws_size,
                              hipStream_t stream)
{
    const float* X     = (const float*)d_in[0];
    const float* emb   = (const float*)d_in[1];
    const float* num_W = (const float*)d_in[2];
    const float* num_b = (const float*)d_in[3];
    const float* Wf    = (const float*)d_in[4];
    const float* bf    = (const float*)d_in[5];
    const float* Wb    = (const float*)d_in[6];
    const float* bb    = (const float*)d_in[7];
    const float* Mu    = (const float*)d_in[8];
    const float* out_W = (const float*)d_in[9];
    const float* out_b = (const float*)d_in[10];
    float* out = (float*)d_out;

    float* ws = (float*)d_ws;
    size_t off = 0;
    float* swp   = ws + off; off += (size_t)BN*8*SN;           // 4 MB
    float* w     = ws + off; off += (size_t)BN*SN;             // 0.5 MB
    float* T     = ws + off; off += (size_t)2*VOCABN*TWOH;     // interleaved
    float* U     = ws + off; off += (size_t)2*8*TWOH;          // interleaved
    float* aArr  = ws + off; off += (size_t)BN*2*SEG*HDIM;     // 2 MB
    float* cArr  = ws + off; off += (size_t)BN*2*SEG*HDIM;     // 2 MB
    float* hstart= ws + off; off += (size_t)BN*2*SEG*HDIM;     // 2 MB
    float* ctxp  = ws + off; off += (size_t)BN*2*SEG*HDIM;     // 2 MB

    hipLaunchKernelGGL(k1_tables,   dim3(2*VOCABN+2),  dim3(512), 0, stream,
                       emb, num_W, num_b, Wf, bf, Wb, bb, T, U);
    hipLaunchKernelGGL(k2_scan<0>,  dim3(BN*2*SEG),    dim3(256), 0, stream,
                       X, T, U, Mu, w, hstart, aArr, cArr, swp, ctxp);
    hipLaunchKernelGGL(k_compose,   dim3(BN*2),        dim3(256), 0, stream,
                       aArr, cArr, hstart);
    hipLaunchKernelGGL(k2_scan<1>,  dim3(BN*2*SEG),    dim3(256), 0, stream,
                       X, T, U, Mu, w, hstart, aArr, cArr, swp, ctxp);
    hipLaunchKernelGGL(k3_softmax,  dim3(BN),          dim3(256), 0, stream,
                       swp, w);
    hipLaunchKernelGGL(k2_scan<2>,  dim3(BN*2*SEG),    dim3(256), 0, stream,
                       X, T, U, Mu, w, hstart, aArr, cArr, swp, ctxp);
    hipLaunchKernelGGL(k5_out,      dim3(BN),          dim3(512), 0, stream,
                       ctxp, out_W, out_b, out);
}